// Round 1
// baseline (634.650 us; speedup 1.0000x reference)
//
#include <hip/hip_runtime.h>
#include <stdint.h>

typedef unsigned long long ull;

// sizes: b=64, f=4, v=256, d=16384, ITERS=10
// d words (u64) = 256, v words = 4
//
// ws layout (bytes):
//   in_bits [64][256] ull        @ 0         (131072)
//   est0    [64][4][256] ull     @ 131072    (524288)
//   est1    [64][4][256] ull     @ 655360    (524288)
//   cbw     [4][256][256] ull    @ 1179648   (2097152)   [f][w][v] : bit l of word = sign cb[f][v][w*64+l]
//   cbT     [4][4][16384] ull    @ 3276800   (2097152)   [f][j][d] : bit l of word = sign cb[f][j*64+l][d]
// total ~5.25 MB
//
// bit convention: bit = 1  <=>  value == -1;  product of bipolars = XOR of bits.

__global__ void pack_bits(const float* __restrict__ src, ull* __restrict__ dst, int nwords) {
    int gw   = (int)((blockIdx.x * blockDim.x + threadIdx.x) >> 6);
    int lane = threadIdx.x & 63;
    if (gw >= nwords) return;
    float x = src[(size_t)gw * 64 + lane];
    ull m = __ballot(x < 0.0f);
    if (lane == 0) dst[gw] = m;
}

// wave per (f,w,v): read cb[f][v][w*64+lane] (coalesced 256B), ballot -> cbw[f][w][v]
__global__ void pack_cbw(const float* __restrict__ cb, ull* __restrict__ cbw) {
    int gw   = (int)((blockIdx.x * blockDim.x + threadIdx.x) >> 6);
    int lane = threadIdx.x & 63;
    int f = gw >> 16, rem = gw & 65535, w = rem >> 8, v = rem & 255;
    float x = cb[(size_t)(f * 256 + v) * 16384 + (size_t)w * 64 + lane];
    ull m = __ballot(x < 0.0f);
    if (lane == 0) cbw[(size_t)(f * 256 + w) * 256 + v] = m;
}

// wave per (f,j,d): lane reads cbw[f][d>>6][j*64+lane] (coalesced), extract bit d&63, ballot over v
__global__ void pack_cbT(const ull* __restrict__ cbw, ull* __restrict__ cbT) {
    int gw   = (int)((blockIdx.x * blockDim.x + threadIdx.x) >> 6);
    int lane = threadIdx.x & 63;
    int f = gw >> 16, rem = gw & 65535, j = rem >> 14, d = rem & 16383;
    ull w = cbw[(size_t)(f * 256 + (d >> 6)) * 256 + j * 64 + lane];
    ull m = __ballot((w >> (d & 63)) & 1ull);
    if (lane == 0) cbT[(size_t)(f * 4 + j) * 16384 + d] = m;
}

// one block per (b,f), 1024 threads
__global__ __launch_bounds__(1024) void iter_kernel(
        const ull* __restrict__ in_bits,
        const ull* __restrict__ est_in, ull* __restrict__ est_out,
        const ull* __restrict__ cbw, const ull* __restrict__ cbT) {
    int b = blockIdx.x >> 2, f = blockIdx.x & 3;
    __shared__ ull s_new[256];
    __shared__ int s_part[4][256];
    __shared__ int s_q[256];
    __shared__ ull s_plane[15][4];
    __shared__ int s_Q;
    int t = threadIdx.x;

    // phase A1: new_est bits = input ^ (xor of all est) ^ est_f
    if (t < 256) {
        ull e0 = est_in[(size_t)(b * 4 + 0) * 256 + t];
        ull e1 = est_in[(size_t)(b * 4 + 1) * 256 + t];
        ull e2 = est_in[(size_t)(b * 4 + 2) * 256 + t];
        ull e3 = est_in[(size_t)(b * 4 + 3) * 256 + t];
        ull u  = in_bits[(size_t)b * 256 + t] ^ e0 ^ e1 ^ e2 ^ e3;
        ull ef = (f == 0) ? e0 : ((f == 1) ? e1 : ((f == 2) ? e2 : e3));
        s_new[t] = u ^ ef;
    }
    __syncthreads();

    // phase A2: hamming distances -> q[v] = (sim[v]+16384)/2 = 16384 - popcount
    {
        int q = t >> 8, v = t & 255;
        const ull* cw = cbw + (size_t)f * 65536 + (size_t)(q * 64) * 256 + v;
        int acc = 0;
        #pragma unroll 8
        for (int w = 0; w < 64; ++w)
            acc += __popcll(s_new[q * 64 + w] ^ cw[(size_t)w * 256]);
        s_part[q][v] = acc;
    }
    __syncthreads();
    if (t < 256) {
        int h = s_part[0][t] + s_part[1][t] + s_part[2][t] + s_part[3][t];
        s_q[t] = 16384 - h;  // in [0, 16384]
    }
    __syncthreads();

    // phase A3: Q = sum_v q[v] (wave 15) and bitplanes of q over v (waves 0..14)
    int wv = t >> 6, lane = t & 63;
    if (wv == 15) {
        int ssum = s_q[lane] + s_q[lane + 64] + s_q[lane + 128] + s_q[lane + 192];
        #pragma unroll
        for (int off = 32; off; off >>= 1) ssum += __shfl_xor(ssum, off);
        if (lane == 0) s_Q = ssum;
    } else {
        #pragma unroll
        for (int j = 0; j < 4; ++j) {
            ull m = __ballot(((unsigned)s_q[j * 64 + lane] >> wv) & 1u);
            if (lane == 0) s_plane[wv][j] = m;
        }
    }
    __syncthreads();
    int Q = s_Q;

    // phase B: s[d] = 2Q - 16384*256 - 4*T[d] + 32768*npop[d]
    //   T[d] = sum_v q[v]*cbbit[v,d],  npop[d] = sum_v cbbit[v,d]
    int T[16], npop[16];
    #pragma unroll
    for (int i = 0; i < 16; ++i) { T[i] = 0; npop[i] = 0; }
    #pragma unroll 1
    for (int j = 0; j < 4; ++j) {
        ull colw[16];
        const ull* ct = cbT + ((size_t)(f * 4 + j) << 14) + t;
        #pragma unroll
        for (int i = 0; i < 16; ++i) colw[i] = ct[(size_t)i << 10];
        #pragma unroll
        for (int i = 0; i < 16; ++i) npop[i] += __popcll(colw[i]);
        #pragma unroll 1
        for (int k = 0; k < 15; ++k) {
            ull pk = s_plane[k][j];
            #pragma unroll
            for (int i = 0; i < 16; ++i) T[i] += __popcll(pk & colw[i]) << k;
        }
    }
    #pragma unroll
    for (int i = 0; i < 16; ++i) {
        int s = 2 * Q - 4194304 - 4 * T[i] + 32768 * npop[i];
        ull m = __ballot(s < 0);
        if (lane == 0) est_out[(size_t)(b * 4 + f) * 256 + i * 16 + wv] = m;
    }
}

// final: sim from est directly, argmax|sim| (first-index ties), unpack est to floats
__global__ __launch_bounds__(1024) void final_kernel(
        const ull* __restrict__ est, const ull* __restrict__ cbw, float* __restrict__ out) {
    int b = blockIdx.x >> 2, f = blockIdx.x & 3;
    __shared__ ull s_e[256];
    __shared__ int s_part[4][256];
    __shared__ int s_sim[256];
    int t = threadIdx.x;
    if (t < 256) s_e[t] = est[(size_t)(b * 4 + f) * 256 + t];
    __syncthreads();
    {
        int q = t >> 8, v = t & 255;
        const ull* cw = cbw + (size_t)f * 65536 + (size_t)(q * 64) * 256 + v;
        int acc = 0;
        #pragma unroll 8
        for (int w = 0; w < 64; ++w)
            acc += __popcll(s_e[q * 64 + w] ^ cw[(size_t)w * 256]);
        s_part[q][v] = acc;
    }
    __syncthreads();
    if (t < 256) {
        int h = s_part[0][t] + s_part[1][t] + s_part[2][t] + s_part[3][t];
        s_sim[t] = 16384 - 2 * h;
    }
    __syncthreads();
    int wv = t >> 6, lane = t & 63;
    if (wv == 0) {
        int best_a = -1, best_v = 0;
        #pragma unroll
        for (int c = 0; c < 4; ++c) {
            int v = c * 64 + lane;
            int sv = s_sim[v];
            int a = sv < 0 ? -sv : sv;
            if (a > best_a) { best_a = a; best_v = v; }   // strict > keeps first index
        }
        #pragma unroll
        for (int off = 1; off < 64; off <<= 1) {
            int oa = __shfl_xor(best_a, off);
            int ov = __shfl_xor(best_v, off);
            if (oa > best_a || (oa == best_a && ov < best_v)) { best_a = oa; best_v = ov; }
        }
        if (lane == 0) out[4194304 + b * 4 + f] = (float)best_v;
    }
    // unpack est bits -> +-1.0f
    #pragma unroll
    for (int i = 0; i < 16; ++i) {
        int d = i * 1024 + t;
        ull w = s_e[d >> 6];
        out[((size_t)(b * 4 + f) << 14) + d] = ((w >> (d & 63)) & 1ull) ? -1.0f : 1.0f;
    }
}

extern "C" void kernel_launch(void* const* d_in, const int* in_sizes, int n_in,
                              void* d_out, int out_size, void* d_ws, size_t ws_size,
                              hipStream_t stream) {
    const float* input    = (const float*)d_in[0];
    const float* init_est = (const float*)d_in[1];
    const float* cb       = (const float*)d_in[2];
    float* out = (float*)d_out;
    char* ws = (char*)d_ws;

    ull* in_bits = (ull*)(ws + 0);
    ull* est0    = (ull*)(ws + 131072);
    ull* est1    = (ull*)(ws + 655360);
    ull* cbw     = (ull*)(ws + 1179648);
    ull* cbT     = (ull*)(ws + 3276800);

    // pack input: 64*256 = 16384 words -> 16384*64/256 = 4096 blocks
    pack_bits<<<4096, 256, 0, stream>>>(input, in_bits, 16384);
    // pack init estimates: 64*4*256 = 65536 words -> 16384 blocks
    pack_bits<<<16384, 256, 0, stream>>>(init_est, est0, 65536);
    // pack codebooks (word-major): 4*256*256 = 262144 waves -> 65536 blocks
    pack_cbw<<<65536, 256, 0, stream>>>(cb, cbw);
    // transpose-pack codebooks (v-mask per d): 4*4*16384 = 262144 waves
    pack_cbT<<<65536, 256, 0, stream>>>(cbw, cbT);

    ull* bufs[2] = { est0, est1 };
    for (int i = 0; i < 10; ++i) {
        iter_kernel<<<256, 1024, 0, stream>>>(in_bits, bufs[i & 1], bufs[(i & 1) ^ 1], cbw, cbT);
    }
    // 10 iterations: final est is back in est0
    final_kernel<<<256, 1024, 0, stream>>>(est0, cbw, out);
}

// Round 2
// 375.153 us; speedup vs baseline: 1.6917x; 1.6917x over previous
//
#include <hip/hip_runtime.h>
#include <stdint.h>

typedef unsigned long long ull;
typedef unsigned short ushort_t;
typedef __attribute__((ext_vector_type(8))) short bf16x8;
typedef __attribute__((ext_vector_type(4))) float f32x4;

// sizes: b=64, f=4, v=256, d=16384, ITERS=10; d-words = 256, v-words = 4
//
// ws layout (bytes):
//   in_bits [64][256] ull        @ 0         (131072)
//   est0    [64][4][256] ull     @ 131072    (524288)
//   est1    [64][4][256] ull     @ 655360    (524288)
//   cbw     [4][256][256] ull    @ 1179648   (2097152)  [f][w][v]: bit l = sign cb[f][v][w*64+l]
//   cbT     [4][4][16384] ull    @ 3276800   (2097152)  [f][j][d]: bit l = sign cb[f][j*64+l][d]
//   simAB   [4][64][512] ushort  @ 5373952   (262144)   [..][0:256]=uh bf16, [256:512]=ul bf16
//   offc    [4][16384] int       @ 5636096   (262144)   8192*colsum[f][d]
// total ~5.9 MB
//
// bit convention: bit = 1  <=>  value == -1;  product of bipolars = XOR of bits.

__global__ void pack_bits(const float* __restrict__ src, ull* __restrict__ dst, int nwords) {
    int gw   = (int)((blockIdx.x * blockDim.x + threadIdx.x) >> 6);
    int lane = threadIdx.x & 63;
    if (gw >= nwords) return;
    float x = src[(size_t)gw * 64 + lane];
    ull m = __ballot(x < 0.0f);
    if (lane == 0) dst[gw] = m;
}

__global__ void pack_cbw(const float* __restrict__ cb, ull* __restrict__ cbw) {
    int gw   = (int)((blockIdx.x * blockDim.x + threadIdx.x) >> 6);
    int lane = threadIdx.x & 63;
    int f = gw >> 16, rem = gw & 65535, w = rem >> 8, v = rem & 255;
    float x = cb[(size_t)(f * 256 + v) * 16384 + (size_t)w * 64 + lane];
    ull m = __ballot(x < 0.0f);
    if (lane == 0) cbw[(size_t)(f * 256 + w) * 256 + v] = m;
}

__global__ void pack_cbT(const ull* __restrict__ cbw, ull* __restrict__ cbT) {
    int gw   = (int)((blockIdx.x * blockDim.x + threadIdx.x) >> 6);
    int lane = threadIdx.x & 63;
    int f = gw >> 16, rem = gw & 65535, j = rem >> 14, d = rem & 16383;
    ull w = cbw[(size_t)(f * 256 + (d >> 6)) * 256 + j * 64 + lane];
    ull m = __ballot((w >> (d & 63)) & 1ull);
    if (lane == 0) cbT[(size_t)(f * 4 + j) * 16384 + d] = m;
}

__global__ void make_offc(const ull* __restrict__ cbT, int* __restrict__ offc) {
    int i = blockIdx.x * 256 + threadIdx.x;   // 4*16384
    int f = i >> 14, d = i & 16383;
    int npop = 0;
    #pragma unroll
    for (int j = 0; j < 4; ++j) npop += __popcll(cbT[((size_t)f * 4 + j) * 16384 + d]);
    offc[i] = 8192 * (256 - 2 * npop);        // 8192 * colsum
}

__device__ __forceinline__ ushort_t f2bf(int x) {
    // exact for 0 <= x <= 256 (<= 8 significant bits)
    return (ushort_t)(__float_as_uint((float)x) >> 16);
}

// phase A: one block per (b,f), 512 threads. q[v] = 16384 - hamming(ne, cb_v)
__global__ __launch_bounds__(512) void simA_kernel(
        const ull* __restrict__ in_bits, const ull* __restrict__ est_in,
        const ull* __restrict__ cbw, ushort_t* __restrict__ simAB) {
    int b = blockIdx.x >> 2, f = blockIdx.x & 3;
    __shared__ ull s_ne[256];
    __shared__ short s_hp[2][256];
    int t = threadIdx.x;
    if (t < 256) {
        ull e0 = est_in[(size_t)(b * 4 + 0) * 256 + t];
        ull e1 = est_in[(size_t)(b * 4 + 1) * 256 + t];
        ull e2 = est_in[(size_t)(b * 4 + 2) * 256 + t];
        ull e3 = est_in[(size_t)(b * 4 + 3) * 256 + t];
        ull u  = in_bits[(size_t)b * 256 + t] ^ e0 ^ e1 ^ e2 ^ e3;
        ull ef = (f == 0) ? e0 : ((f == 1) ? e1 : ((f == 2) ? e2 : e3));
        s_ne[t] = u ^ ef;
    }
    __syncthreads();
    int v = t & 255, half = t >> 8;
    const ull* cw = cbw + (size_t)f * 65536 + (size_t)(half * 128) * 256 + v;
    int acc = 0;
    #pragma unroll 8
    for (int w = 0; w < 128; ++w)
        acc += __popcll(s_ne[half * 128 + w] ^ cw[(size_t)w * 256]);
    s_hp[half][v] = (short)acc;
    __syncthreads();
    if (t < 256) {
        int q = 16384 - (s_hp[0][t] + s_hp[1][t]);     // in [0,16384]
        size_t base = ((size_t)(f * 64 + b)) * 512 + t;
        simAB[base]       = f2bf(q >> 8);              // uh in [0,64]
        simAB[base + 256] = f2bf(q & 255);             // ul in [0,255]
    }
}

// phase B: one block per (f, dblk of 256 d), 256 threads (4 waves, wave = 16-row m-tile)
// est_bit(b,d) = ( 256*sum_v uh*cb + sum_v ul*cb < 8192*colsum )
__global__ __launch_bounds__(256) void gemm_kernel(
        const ull* __restrict__ cbT, const ushort_t* __restrict__ simAB,
        const int* __restrict__ offc, ull* __restrict__ est_out) {
    int f = blockIdx.x >> 6, dblk = blockIdx.x & 63;
    __shared__ int4 sB[8192];                  // 128KB, frag order: (kc*16+nt)*64 + lane
    __shared__ unsigned char s_sign[64][256];  // 16KB
    __shared__ int s_off[256];
    int t = threadIdx.x;
    int lane = t & 63, wave = t >> 6;

    if (t < 256) s_off[t] = offc[f * 16384 + dblk * 256 + t];

    // stage B: unpack codebook bits -> bf16 MFMA B-frags in LDS
    #pragma unroll 4
    for (int it = 0; it < 32; ++it) {
        int flat = it * 256 + t;               // over 8 kc * 16 nt * 64 lanes
        int kc = flat >> 10, nt = (flat >> 6) & 15, l = flat & 63;
        int v0 = kc * 32 + ((l >> 4) << 3);
        int d  = dblk * 256 + nt * 16 + (l & 15);
        ull w = cbT[((size_t)f * 4 + (v0 >> 6)) * 16384 + d];
        unsigned bits = (unsigned)(w >> (v0 & 63)) & 0xFFu;
        int4 val;
        val.x = 0x3F803F80 | ((bits & 1u) << 15)        | ((bits & 2u) << 30);
        val.y = 0x3F803F80 | (((bits >> 2) & 1u) << 15) | (((bits >> 2) & 2u) << 30);
        val.z = 0x3F803F80 | (((bits >> 4) & 1u) << 15) | (((bits >> 4) & 2u) << 30);
        val.w = 0x3F803F80 | (((bits >> 6) & 1u) << 15) | (((bits >> 6) & 2u) << 30);
        sB[flat] = val;
    }

    // preload A frags from global sim (L2-resident, 16B per lane, exact bf16 ints)
    bf16x8 Ahi[8], Alo[8];
    int m0 = wave * 16;
    const ushort_t* abase = simAB + ((size_t)(f * 64 + m0 + (lane & 15))) * 512 + ((lane >> 4) << 3);
    #pragma unroll
    for (int kc = 0; kc < 8; ++kc) {
        Ahi[kc] = *(const bf16x8*)(abase + kc * 32);
        Alo[kc] = *(const bf16x8*)(abase + 256 + kc * 32);
    }
    __syncthreads();

    for (int nt = 0; nt < 16; ++nt) {
        f32x4 acch = {0.f, 0.f, 0.f, 0.f}, accl = {0.f, 0.f, 0.f, 0.f};
        #pragma unroll
        for (int kc = 0; kc < 8; ++kc) {
            bf16x8 B = *(const bf16x8*)&sB[(kc * 16 + nt) * 64 + lane];
            acch = __builtin_amdgcn_mfma_f32_16x16x32_bf16(Ahi[kc], B, acch, 0, 0, 0);
            accl = __builtin_amdgcn_mfma_f32_16x16x32_bf16(Alo[kc], B, accl, 0, 0, 0);
        }
        int dl = nt * 16 + (lane & 15);
        float offf = (float)s_off[dl];
        #pragma unroll
        for (int r = 0; r < 4; ++r) {
            float S = 256.0f * acch[r] + accl[r];      // exact int < 2^23
            s_sign[m0 + ((lane >> 4) << 2) + r][dl] = (S < offf) ? 1 : 0;
        }
    }
    __syncthreads();

    if (t < 256) {
        int b = t >> 2, w = t & 3;
        ull m = 0;
        #pragma unroll
        for (int j2 = 0; j2 < 64; ++j2)
            m |= ((ull)s_sign[b][w * 64 + j2]) << j2;
        est_out[((size_t)(b * 4 + f)) * 256 + dblk * 4 + w] = m;
    }
}

// final: sim from est bits, argmax|sim| (first-index ties), unpack est to floats
__global__ __launch_bounds__(1024) void final_kernel(
        const ull* __restrict__ est, const ull* __restrict__ cbw, float* __restrict__ out) {
    int b = blockIdx.x >> 2, f = blockIdx.x & 3;
    __shared__ ull s_e[256];
    __shared__ int s_part[4][256];
    __shared__ int s_sim[256];
    int t = threadIdx.x;
    if (t < 256) s_e[t] = est[(size_t)(b * 4 + f) * 256 + t];
    __syncthreads();
    {
        int q = t >> 8, v = t & 255;
        const ull* cw = cbw + (size_t)f * 65536 + (size_t)(q * 64) * 256 + v;
        int acc = 0;
        #pragma unroll 8
        for (int w = 0; w < 64; ++w)
            acc += __popcll(s_e[q * 64 + w] ^ cw[(size_t)w * 256]);
        s_part[q][v] = acc;
    }
    __syncthreads();
    if (t < 256) {
        int h = s_part[0][t] + s_part[1][t] + s_part[2][t] + s_part[3][t];
        s_sim[t] = 16384 - 2 * h;
    }
    __syncthreads();
    int wv = t >> 6, lane = t & 63;
    if (wv == 0) {
        int best_a = -1, best_v = 0;
        #pragma unroll
        for (int c = 0; c < 4; ++c) {
            int v = c * 64 + lane;
            int sv = s_sim[v];
            int a = sv < 0 ? -sv : sv;
            if (a > best_a) { best_a = a; best_v = v; }
        }
        #pragma unroll
        for (int off = 1; off < 64; off <<= 1) {
            int oa = __shfl_xor(best_a, off);
            int ov = __shfl_xor(best_v, off);
            if (oa > best_a || (oa == best_a && ov < best_v)) { best_a = oa; best_v = ov; }
        }
        if (lane == 0) out[4194304 + b * 4 + f] = (float)best_v;
    }
    #pragma unroll
    for (int i = 0; i < 16; ++i) {
        int d = i * 1024 + t;
        ull w = s_e[d >> 6];
        out[((size_t)(b * 4 + f) << 14) + d] = ((w >> (d & 63)) & 1ull) ? -1.0f : 1.0f;
    }
}

extern "C" void kernel_launch(void* const* d_in, const int* in_sizes, int n_in,
                              void* d_out, int out_size, void* d_ws, size_t ws_size,
                              hipStream_t stream) {
    const float* input    = (const float*)d_in[0];
    const float* init_est = (const float*)d_in[1];
    const float* cb       = (const float*)d_in[2];
    float* out = (float*)d_out;
    char* ws = (char*)d_ws;

    ull* in_bits    = (ull*)(ws + 0);
    ull* est0       = (ull*)(ws + 131072);
    ull* est1       = (ull*)(ws + 655360);
    ull* cbw        = (ull*)(ws + 1179648);
    ull* cbT        = (ull*)(ws + 3276800);
    ushort_t* simAB = (ushort_t*)(ws + 5373952);
    int* offc       = (int*)(ws + 5636096);

    pack_bits<<<4096, 256, 0, stream>>>(input, in_bits, 16384);
    pack_bits<<<16384, 256, 0, stream>>>(init_est, est0, 65536);
    pack_cbw<<<65536, 256, 0, stream>>>(cb, cbw);
    pack_cbT<<<65536, 256, 0, stream>>>(cbw, cbT);
    make_offc<<<256, 256, 0, stream>>>(cbT, offc);

    ull* bufs[2] = { est0, est1 };
    for (int i = 0; i < 10; ++i) {
        simA_kernel<<<256, 512, 0, stream>>>(in_bits, bufs[i & 1], cbw, simAB);
        gemm_kernel<<<256, 256, 0, stream>>>(cbT, simAB, offc, bufs[(i & 1) ^ 1]);
    }
    final_kernel<<<256, 1024, 0, stream>>>(est0, cbw, out);
}